// Round 1
// 706.366 us; speedup vs baseline: 1.0388x; 1.0388x over previous
//
#include <hip/hip_runtime.h>
#include <cstdint>

typedef _Float16 half_t;
typedef _Float16 half8  __attribute__((ext_vector_type(8)));
typedef _Float16 half4_t __attribute__((ext_vector_type(4)));
typedef _Float16 h2f    __attribute__((ext_vector_type(2)));
typedef float    floatx4 __attribute__((ext_vector_type(4)));

#define KNN 40
#define KVPAD 124

// ---------------- workspace layout (bytes) ----------------
#define WS_NF16    0ull
#define WS_EMB16   25600000ull
#define WS_WKVT    28672000ull
#define WS_WQ4     29065216ull   // 2 layers x 65536 B
#define WS_W1A4    29196288ull
#define WS_W1B4    29327360ull
#define WS_W24     29458432ull
#define WS_QBIAS   29589504ull
#define WS_WOFTMP  29590528ull
#define WS_ZERO    29721600ull
#define WS_EF16    29721856ull
#define WS_TOTAL_FULL (WS_EF16 + 128000000ull)

// global -> LDS direct copy, 16 B per lane, dest = wave-uniform base + lane*16
__device__ __forceinline__ void ld16(const void* g, void* l) {
  __builtin_amdgcn_global_load_lds(
      (const __attribute__((address_space(1))) unsigned int*)(uintptr_t)g,
      (__attribute__((address_space(3))) unsigned int*)(uintptr_t)l, 16, 0, 0);
}

__device__ __forceinline__ float dot4(half4_t a, half4_t b, float s) {
  s = __builtin_amdgcn_fdot2((h2f){a[0], a[1]}, (h2f){b[0], b[1]}, s, false);
  s = __builtin_amdgcn_fdot2((h2f){a[2], a[3]}, (h2f){b[2], b[3]}, s, false);
  return s;
}

// ---------------------------------------------------------------------------
__global__ __launch_bounds__(256) void cvt_kernel(
    const float* __restrict__ src, half_t* __restrict__ dst, int n8) {
  int stride = gridDim.x * 256;
  for (int i = blockIdx.x * 256 + threadIdx.x; i < n8; i += stride) {
    float4 a = *((const float4*)src + 2 * (size_t)i);
    float4 b = *((const float4*)src + 2 * (size_t)i + 1);
    half8 h;
    h[0] = (half_t)a.x; h[1] = (half_t)a.y; h[2] = (half_t)a.z; h[3] = (half_t)a.w;
    h[4] = (half_t)b.x; h[5] = (half_t)b.y; h[6] = (half_t)b.z; h[7] = (half_t)b.w;
    *((half8*)dst + i) = h;
  }
}

// decode t -> (l, d4, j, e) for the 4-row-pack layout: idx = l*16384 + (d4*128+j)*4 + e
#define PK_DECODE(t) int l = (t) >> 14; int u = (t) & 16383; \
  int d4 = u >> 9; int v = u & 511; int j = v >> 2; int e = v & 3;

__global__ __launch_bounds__(256) void precompute_w(
    const float* __restrict__ Wq, const float* __restrict__ Wk,
    const float* __restrict__ Wv, const float* __restrict__ Wo,
    const float* __restrict__ fc1, const float* __restrict__ fc2,
    const float* __restrict__ time_b,
    half_t* __restrict__ WkvT, float* __restrict__ qbias,
    float* __restrict__ woftmp, half_t* __restrict__ Wq4,
    half_t* __restrict__ W1b4, half_t* __restrict__ W24,
    half_t* __restrict__ zrow)
{
  int blk = blockIdx.x, tid = threadIdx.x;
  if (blk < 768) {
    int t = blk * 256 + tid;            // [0, 2*256*384)
    int l = t / 98304;
    int r = t - l * 98304;
    int n = r / 384;
    int k = r - n * 384;
    float vv = (n < 128) ? Wk[l * 49152 + k * 128 + n]
                         : Wv[l * 49152 + k * 128 + (n - 128)];
    WkvT[t] = (half_t)vv;
  } else if (blk == 768) {
    if (tid < 128) zrow[tid] = (half_t)0.f;
    int l = tid >> 7, j = tid & 127;
    float s = 0.f;
    for (int d = 0; d < 128; ++d)
      s += cosf(time_b[d]) * Wq[l * 32768 + (128 + d) * 128 + j];
    qbias[l * 128 + j] = s;
  } else if (blk < 897) {
    int t = (blk - 769) * 256 + tid;    // Wofc1 = Wo @ fc1_top (f32 temp)
    int l = t >> 14;
    int r = t & 16383;
    int dd = r >> 7, j = r & 127;
    float s = 0.f;
    for (int m = 0; m < 128; ++m)
      s += Wo[l * 16384 + dd * 128 + m] * fc1[l * 32768 + m * 128 + j];
    woftmp[t] = s;
  } else if (blk < 1025) {
    int t = (blk - 897) * 256 + tid;
    PK_DECODE(t);
    Wq4[t] = (half_t)Wq[l * 32768 + (4 * d4 + e) * 128 + j];
  } else if (blk < 1153) {
    int t = (blk - 1025) * 256 + tid;
    PK_DECODE(t);
    W1b4[t] = (half_t)fc1[l * 32768 + (128 + 4 * d4 + e) * 128 + j];
  } else {
    int t = (blk - 1153) * 256 + tid;
    PK_DECODE(t);
    W24[t] = (half_t)fc2[l * 16384 + (4 * d4 + e) * 128 + j];
  }
}

__global__ __launch_bounds__(256) void precompute_w2(
    const float* __restrict__ woftmp, half_t* __restrict__ W1a4) {
  int t = blockIdx.x * 256 + threadIdx.x;
  PK_DECODE(t);
  W1a4[t] = (half_t)woftmp[l * 16384 + (4 * d4 + e) * 128 + j];
}

// ---------------------------------------------------------------------------
// Fused hop aggregation. 512 thr = 8 waves, 3 batches/block (120 kv rows).
// v2: K-step 32 software pipeline -- 4-deep A (4x8KB), 2-deep B (2x16KB),
// raw s_barrier + hand-counted s_waitcnt vmcnt(N) (never 0 in the main loop),
// so gather/weight prefetches stay in flight across barriers instead of being
// drained by __syncthreads' implicit vmcnt(0). Epilogue uses raw barriers with
// counted waits so W1a/W1b/W24 stages overlap the attention phases.
// K-chunk order: ne(0-3), ef(4-7), et/cos(8-11); weight kc remaps accordingly.
// ---------------------------------------------------------------------------
template <bool EF16, bool L1DIR>
__global__ __launch_bounds__(512, 4) void hop_kernel(
    const float*  __restrict__ nf,
    const half_t* __restrict__ ne16,     // L0: nf16 (gather via neigh); L1: emb116 direct
    const half_t* __restrict__ ef16,
    const float*  __restrict__ ef32,
    const int*    __restrict__ src_idx,
    const float*  __restrict__ tsv,
    const int*    __restrict__ neigh,
    const int*    __restrict__ eidx,
    const float*  __restrict__ etimes,
    const float*  __restrict__ tw,
    const float*  __restrict__ tb,
    const half_t* __restrict__ Wq4_l,
    const float*  __restrict__ qbias_l,
    const half_t* __restrict__ WkvT_l,
    const half_t* __restrict__ W1a4_l,
    const half_t* __restrict__ W1b4_l,
    const half_t* __restrict__ W24_l,
    const half_t* __restrict__ zrow,
    half_t* __restrict__ out16,
    float*  __restrict__ out32)
{
  // LDS: A bufs 4x8K @0, B bufs 2x16K @32768, persists @65536
  __shared__ __align__(16) char smem[71360];
  half_t* BTs  = (half_t*)(smem + 32768);
  half_t* kvT  = (half_t*)(smem + 32768);
  float*  tw_s = (float*)(smem + 65536);
  float*  tb_s = (float*)(smem + 66048);
  float*  qs   = (float*)(smem + 66560);
  half_t* s16  = (half_t*)(smem + 68096);
  half_t* aO16 = (half_t*)(smem + 68864);
  half_t* h116 = (half_t*)(smem + 69632);
  float*  scs  = (float*)(smem + 70400);

  const int tid = threadIdx.x;
  const int bbase = blockIdx.x * 3;
  const int lane = tid & 63, wv = tid >> 6;
  const int l15 = lane & 15, q4 = lane >> 4;
  const int wm = (wv & 1) * 64, wn = (wv >> 1) * 64;

  // ---- setup ----
  if (tid < 128) { tw_s[tid] = tw[tid]; tb_s[tid] = tb[tid]; }
  if (tid < 96) {
    int g = tid >> 5, d4 = tid & 31;
    float4 v4 = *(const float4*)(nf + (size_t)src_idx[bbase + g] * 128 + d4 * 4);
    half4_t h;
    h[0] = (half_t)v4.x; h[1] = (half_t)v4.y; h[2] = (half_t)v4.z; h[3] = (half_t)v4.w;
    *(half4_t*)(s16 + g * 128 + d4 * 4) = h;
  }

  // preload the score mask so the scores phase has no global load in it
  int neighval = 1;
  if (tid < 240) {
    int g = tid / 80, rem = tid - g * 80, n = rem % 40;
    neighval = neigh[(bbase + g) * KNN + n];
  }

  // per-lane A-row setup (row r = wv*16 + l15, folded q4*8 column offset)
  const int r = wv * 16 + l15;
  const bool valid = (r < 120);
  float dval = 0.f;
  const half_t* pNE = zrow + q4 * 8;
  const half_t* pEF = zrow + q4 * 8;
  if (valid) {
    int g = r / 40, n = r - g * 40;
    int bg = bbase + g;
    int rowidx = bg * KNN + n;
    dval = tsv[L1DIR ? bg : (bg / 40)] - etimes[rowidx];
    pNE = (L1DIR ? ne16 + (size_t)rowidx * 128
                 : ne16 + (size_t)neigh[rowidx] * 128) + q4 * 8;
    if (EF16) pEF = ef16 + (size_t)eidx[rowidx] * 128 + q4 * 8;
  }
  // fallback EF(f32) per-thread setup (4 threads/row, 8 floats each per step)
  const float* gbe32 = nullptr;
  const int rr = tid >> 2, pp = tid & 3;
  if (!EF16 && rr < 120) {
    int g2 = rr / 40, n2 = rr - g2 * 40;
    gbe32 = ef32 + (size_t)eidx[(bbase + g2) * KNN + n2] * 128 + pp * 8;
  }

  // B per-lane source base (f16 elems); WkvT is [n(256)][k(384)]
  const half_t* bBase = WkvT_l + (size_t)(2 * wv * 16 + l15) * 384 + q4 * 8;

  floatx4 acc[4][4];
  #pragma unroll
  for (int mi = 0; mi < 4; ++mi)
    #pragma unroll
    for (int ni = 0; ni < 4; ++ni) acc[mi][ni] = (floatx4){0.f, 0.f, 0.f, 0.f};

  // step s -> weight k-chunk: ne s<4 -> s ; ef 4..7 -> s+4 ; et 8..11 -> s-4
  auto issB = [&](int s, char* bb) {
    int kc = (s < 4) ? s : (s < 8 ? s + 4 : s - 4);
    const half_t* bp = bBase + kc * 32;
    ld16(bp,        bb + wv * 2048);          // colgroup 2wv
    ld16(bp + 6144, bb + wv * 2048 + 1024);   // colgroup 2wv+1
  };
  auto issA = [&](int s, char* ab) {          // s in 0..7 (gather steps)
    const half_t* p = (s < 4) ? pNE + s * 32 : pEF + (s - 4) * 32;
    ld16(p, ab + wv * 1024);
  };
  auto cosA = [&](int s, char* ab) {          // s in 8..11 (time-encoding)
    int cb = (s - 8) * 32 + q4 * 8;
    half8 h;
    #pragma unroll
    for (int j = 0; j < 8; ++j) {
      float ang = __builtin_fmaf(dval, tw_s[cb + j], tb_s[cb + j]);
      h[j] = valid ? (half_t)__cosf(ang) : (half_t)0.f;
    }
    *(half8*)(ab + wv * 1024 + lane * 16) = h;
  };
  auto efA32 = [&](int s, char* ab) {         // fallback f32 edge feats
    half8 h = {};
    if (rr < 120) {
      const float* gb = gbe32 + (s - 4) * 32;
      float4 v0 = ((const float4*)gb)[0];
      float4 v1 = ((const float4*)gb)[1];
      h[0] = (half_t)v0.x; h[1] = (half_t)v0.y; h[2] = (half_t)v0.z; h[3] = (half_t)v0.w;
      h[4] = (half_t)v1.x; h[5] = (half_t)v1.y; h[6] = (half_t)v1.z; h[7] = (half_t)v1.w;
    }
    *(half8*)(ab + (rr >> 4) * 1024 + pp * 256 + (rr & 15) * 16) = h;
  };
  auto mfma_step = [&](const char* ab, const char* bb) {
    const half_t* A  = (const half_t*)ab;
    const half_t* Bp = (const half_t*)bb;
    half8 a[4];
    #pragma unroll
    for (int mi = 0; mi < 4; ++mi)
      a[mi] = *(const half8*)(A + ((wv & 1) * 4 + mi) * 512 + q4 * 128 + l15 * 8);
    #pragma unroll
    for (int ni = 0; ni < 4; ++ni) {
      half8 bfr = *(const half8*)(Bp + (((wn >> 4) + ni) * 512) + q4 * 128 + l15 * 8);
      #pragma unroll
      for (int mi = 0; mi < 4; ++mi)
        acc[mi][ni] = __builtin_amdgcn_mfma_f32_16x16x32_f16(a[mi], bfr, acc[mi][ni], 0, 0, 0);
    }
  };
  auto stageW = [&](const half_t* wsrc, char* dst) {
    const char* sw = (const char*)wsrc + wv * 4096 + lane * 16;
    char* dw = dst + wv * 4096;
    ld16(sw, dw); ld16(sw + 1024, dw + 1024);
    ld16(sw + 2048, dw + 2048); ld16(sw + 3072, dw + 3072);
  };

#define AB(i) (smem + (i) * 8192)
#define BB(i) (smem + 32768 + (i) * 16384)
#define FENCE asm volatile("" ::: "memory")

  // ---- prologue: issue B0,B1 + all 4 ne A-chunks; sync setup LDS only ----
  FENCE;
  issB(0, BB(0)); issB(1, BB(1));
  issA(0, AB(0)); issA(1, AB(1)); issA(2, AB(2)); issA(3, AB(3));
  asm volatile("s_waitcnt lgkmcnt(0)" ::: "memory");
  __builtin_amdgcn_s_barrier(); FENCE;

  // ---- K-loop: 12 steps, counted vmcnt (WE = EF16 counts, WF = f32-EF counts)
  // Wait counts derived from the FIFO issue order (B=2 loads, A=1 load/step).
#define HSTEP(s, WE, WF, ...)                                                   \
  asm volatile("s_waitcnt vmcnt(%0) lgkmcnt(0)" :: "i"(EF16 ? (WE) : (WF))      \
               : "memory");                                                     \
  __builtin_amdgcn_s_barrier(); FENCE;                                          \
  mfma_step(AB((s) & 3), BB((s) & 1));                                          \
  FENCE; __builtin_amdgcn_s_barrier(); FENCE;                                   \
  __VA_ARGS__

  HSTEP(0, 3, 3, issB(2, BB(0)); if constexpr (EF16) issA(4, AB(0)); else efA32(4, AB(0));)
  HSTEP(1, 5, 4, issB(3, BB(1)); if constexpr (EF16) issA(5, AB(1)); else efA32(5, AB(1));)
  HSTEP(2, 7, 5, issB(4, BB(0)); if constexpr (EF16) issA(6, AB(2)); else efA32(6, AB(2));)
  HSTEP(3, 9, 6, issB(5, BB(1)); if constexpr (EF16) issA(7, AB(3)); else efA32(7, AB(3));)
  HSTEP(4, 4, 2, issB(6, BB(0)); cosA(8, AB(0));)
  HSTEP(5, 3, 2, issB(7, BB(1)); cosA(9, AB(1));)
  HSTEP(6, 2, 2, issB(8, BB(0)); cosA(10, AB(2));)
  HSTEP(7, 2, 2, issB(9, BB(1)); cosA(11, AB(3));)
  HSTEP(8, 2, 2, issB(10, BB(0));)
  HSTEP(9, 2, 2, issB(11, BB(1));)
  HSTEP(10, 2, 2, )
  HSTEP(11, 0, 0, )
#undef HSTEP

  // ---- epilogue (queue empty here). Stage W1a early; it stays in flight. ----
  stageW(W1a4_l, smem);                 // -> A region [0,32768)

  // kk -> kvT (cols 0..127)
  if (wv < 4) {
    #pragma unroll
    for (int mi = 0; mi < 4; ++mi) {
      int row0 = wm + mi * 16 + q4 * 4;
      if (row0 < 120) {
        #pragma unroll
        for (int ni = 0; ni < 4; ++ni) {
          int col = wn + ni * 16 + l15;
          half4_t h;
          h[0] = (half_t)acc[mi][ni][0]; h[1] = (half_t)acc[mi][ni][1];
          h[2] = (half_t)acc[mi][ni][2]; h[3] = (half_t)acc[mi][ni][3];
          *(half4_t*)(kvT + col * KVPAD + row0) = h;
        }
      }
    }
  }

  // q = src @ Wq_top + qbias (Wq4 read straight from L2; moved post-loop so it
  // no longer serializes the prologue or shares the B LDS region)
  if (tid < 384) {
    int gq = tid >> 7, jj = tid & 127;
    float s = qbias_l[jj];
    #pragma unroll 8
    for (int d4 = 0; d4 < 32; ++d4) {
      half4_t w = *(const half4_t*)(Wq4_l + (d4 * 128 + jj) * 4);
      half4_t a = *(const half4_t*)(s16 + gq * 128 + d4 * 4);
      s = dot4(w, a, s);
    }
    qs[gq * 128 + jj] = s;
  }
  asm volatile("s_waitcnt lgkmcnt(0)" ::: "memory");
  __builtin_amdgcn_s_barrier(); FENCE;   // E1: kvT + qs visible (W1a still in flight)

  // ---- scores (mask preloaded in setup) ----
  if (tid < 240) {
    int g = tid / 80;
    int rem = tid - g * 80;
    int hh = rem / 40;
    int n = rem - hh * 40;
    const float* qrow = qs + g * 128 + hh * 64;
    int row = g * 40 + n;
    float s = 0.f;
    #pragma unroll 8
    for (int d = 0; d < 64; ++d)
      s += qrow[d] * (float)kvT[(hh * 64 + d) * KVPAD + row];
    scs[tid] = (neighval == 0) ? -1e9f : s * 0.125f;
  }
  asm volatile("s_waitcnt lgkmcnt(0)" ::: "memory");
  __builtin_amdgcn_s_barrier(); FENCE;   // E2: scs visible

  // ---- softmax (waves 0..5) + vv -> kvT (waves 4..7) ----
  if (wv < 6) {
    float v = (lane < 40) ? scs[wv * 40 + lane] : -1e30f;
    float m = v;
    #pragma unroll
    for (int o = 32; o; o >>= 1) m = fmaxf(m, __shfl_xor(m, o));
    float e = (lane < 40) ? __expf(v - m) : 0.f;
    float ssum = e;
    #pragma unroll
    for (int o = 32; o; o >>= 1) ssum += __shfl_xor(ssum, o);
    if (lane < 40) scs[wv * 40 + lane] = e / ssum;
  }
  if (wv >= 4) {
    #pragma unroll
    for (int mi = 0; mi < 4; ++mi) {
      int row0 = wm + mi * 16 + q4 * 4;
      if (row0 < 120) {
        #pragma unroll
        for (int ni = 0; ni < 4; ++ni) {
          int col = wn - 128 + ni * 16 + l15;
          half4_t h;
          h[0] = (half_t)acc[mi][ni][0]; h[1] = (half_t)acc[mi][ni][1];
          h[2] = (half_t)acc[mi][ni][2]; h[3] = (half_t)acc[mi][ni][3];
          *(half4_t*)(kvT + col * KVPAD + row0) = h;
        }
      }
    }
  }
  asm volatile("s_waitcnt lgkmcnt(0)" ::: "memory");
  __builtin_amdgcn_s_barrier(); FENCE;   // E3: attn + vv visible

  // ---- attnOut -> aO16 ----
  if (tid < 384) {
    int g = tid >> 7, dcol = tid & 127, hh = dcol >> 6;
    const float* attn = scs + (g * 2 + hh) * 40;
    const half_t* vcol = kvT + dcol * KVPAD + g * 40;
    float s = 0.f;
    #pragma unroll 8
    for (int n = 0; n < 40; ++n) s += attn[n] * (float)vcol[n];
    aO16[g * 128 + dcol] = (half_t)s;
  }
  asm volatile("s_waitcnt lgkmcnt(0)" ::: "memory");
  __builtin_amdgcn_s_barrier(); FENCE;   // E4: aO16 visible; kvT dead

  // ---- stage W1b -> BTs (kvT region, now dead); wait only for W1a ----
  stageW(W1b4_l, (char*)BTs);
  asm volatile("s_waitcnt vmcnt(4)" ::: "memory");   // W1a landed, W1b in flight
  __builtin_amdgcn_s_barrier(); FENCE;   // E4b: W1a visible to all waves

  float p1 = 0.f;
  if (tid < 384) {
    int g = tid >> 7, jj = tid & 127;
    #pragma unroll 8
    for (int d4 = 0; d4 < 32; ++d4) {
      half4_t w = *(const half4_t*)((const half_t*)smem + (d4 * 128 + jj) * 4);
      half4_t a = *(const half4_t*)(aO16 + g * 128 + d4 * 4);
      p1 = dot4(w, a, p1);
    }
  }
  FENCE; __builtin_amdgcn_s_barrier(); FENCE;        // E5: A region free

  // ---- stage W24 -> A region; wait only for W1b; h1 pass2 + relu ----
  stageW(W24_l, smem);
  asm volatile("s_waitcnt vmcnt(4)" ::: "memory");   // W1b landed, W24 in flight
  __builtin_amdgcn_s_barrier(); FENCE;   // E5b: W1b visible
  if (tid < 384) {
    int g = tid >> 7, jj = tid & 127;
    float p2 = p1;
    #pragma unroll 8
    for (int d4 = 0; d4 < 32; ++d4) {
      half4_t w = *(const half4_t*)(BTs + (d4 * 128 + jj) * 4);
      half4_t a = *(const half4_t*)(s16 + g * 128 + d4 * 4);
      p2 = dot4(w, a, p2);
    }
    h116[g * 128 + jj] = (half_t)fmaxf(p2, 0.f);
  }
  asm volatile("s_waitcnt vmcnt(0) lgkmcnt(0)" ::: "memory");
  __builtin_amdgcn_s_barrier(); FENCE;   // E6: h116 + W24 visible

  // ---- fc2 -> out ----
  if (tid < 384) {
    int g = tid >> 7, ii = tid & 127;
    float s = 0.f;
    #pragma unroll 8
    for (int j4 = 0; j4 < 32; ++j4) {
      half4_t w = *(const half4_t*)((const half_t*)smem + (j4 * 128 + ii) * 4);
      half4_t a = *(const half4_t*)(h116 + g * 128 + j4 * 4);
      s = dot4(w, a, s);
    }
    if (L1DIR) out32[(size_t)(bbase + g) * 128 + ii] = s;
    else       out16[(size_t)(bbase + g) * 128 + ii] = (half_t)s;
  }
#undef AB
#undef BB
#undef FENCE
}

// ---------------------------------------------------------------------------
extern "C" void kernel_launch(void* const* d_in, const int* in_sizes, int n_in,
                              void* d_out, int out_size, void* d_ws, size_t ws_size,
                              hipStream_t stream) {
  const float* nf      = (const float*)d_in[0];
  const float* ef      = (const float*)d_in[1];
  const float* tw      = (const float*)d_in[2];
  const float* tb      = (const float*)d_in[3];
  const float* Wq      = (const float*)d_in[4];
  const float* Wk      = (const float*)d_in[5];
  const float* Wv      = (const float*)d_in[6];
  const float* Wo      = (const float*)d_in[7];
  const float* fc1     = (const float*)d_in[8];
  const float* fc2     = (const float*)d_in[9];
  const int*   srcn    = (const int*)d_in[10];
  const float* ts      = (const float*)d_in[11];
  const int*   neigh2  = (const int*)d_in[12];
  const int*   eidx2   = (const int*)d_in[13];
  const float* etimes2 = (const float*)d_in[14];
  const int*   neigh1  = (const int*)d_in[15];
  const int*   eidx1   = (const int*)d_in[16];
  const float* etimes1 = (const float*)d_in[17];

  char* ws = (char*)d_ws;
  half_t* nf16   = (half_t*)(ws + WS_NF16);
  half_t* emb116 = (half_t*)(ws + WS_EMB16);
  half_t* WkvT16 = (half_t*)(ws + WS_WKVT);
  half_t* Wq4    = (half_t*)(ws + WS_WQ4);
  half_t* W1a4   = (half_t*)(ws + WS_W1A4);
  half_t* W1b4   = (half_t*)(ws + WS_W1B4);
  half_t* W24    = (half_t*)(ws + WS_W24);
  float*  qbias  = (float*)(ws + WS_QBIAS);
  float*  woftmp = (float*)(ws + WS_WOFTMP);
  half_t* zrow   = (half_t*)(ws + WS_ZERO);
  half_t* ef16   = (half_t*)(ws + WS_EF16);

  bool full = (ws_size >= WS_TOTAL_FULL);

  cvt_kernel<<<dim3(2048), dim3(256), 0, stream>>>(nf, nf16, 1600000);
  if (full)
    cvt_kernel<<<dim3(4096), dim3(256), 0, stream>>>(ef, ef16, 8000000);
  precompute_w<<<dim3(1281), dim3(256), 0, stream>>>(
      Wq, Wk, Wv, Wo, fc1, fc2, tb, WkvT16, qbias, woftmp, Wq4, W1b4, W24, zrow);
  precompute_w2<<<dim3(128), dim3(256), 0, stream>>>(woftmp, W1a4);

  if (full) {
    hop_kernel<true, false><<<dim3(4000), dim3(512), 0, stream>>>(
        nf, nf16, ef16, ef, neigh2, ts, neigh1, eidx1, etimes1, tw, tb,
        Wq4, qbias, WkvT16, W1a4, W1b4, W24, zrow, emb116, nullptr);
    hop_kernel<true, true><<<dim3(100), dim3(512), 0, stream>>>(
        nf, emb116, ef16, ef, srcn, ts, neigh2, eidx2, etimes2, tw, tb,
        Wq4 + 16384, qbias + 128, WkvT16 + 98304, W1a4 + 16384, W1b4 + 16384,
        W24 + 16384, zrow, emb116, (float*)d_out);
  } else {
    hop_kernel<false, false><<<dim3(4000), dim3(512), 0, stream>>>(
        nf, nf16, ef16, ef, neigh2, ts, neigh1, eidx1, etimes1, tw, tb,
        Wq4, qbias, WkvT16, W1a4, W1b4, W24, zrow, emb116, nullptr);
    hop_kernel<false, true><<<dim3(100), dim3(512), 0, stream>>>(
        nf, emb116, ef16, ef, srcn, ts, neigh2, eidx2, etimes2, tw, tb,
        Wq4 + 16384, qbias + 128, WkvT16 + 98304, W1a4 + 16384, W1b4 + 16384,
        W24 + 16384, zrow, emb116, (float*)d_out);
  }
}

// Round 3
// 688.213 us; speedup vs baseline: 1.0662x; 1.0264x over previous
//
#include <hip/hip_runtime.h>
#include <cstdint>

typedef _Float16 half_t;
typedef _Float16 half8  __attribute__((ext_vector_type(8)));
typedef _Float16 half4_t __attribute__((ext_vector_type(4)));
typedef _Float16 h2f    __attribute__((ext_vector_type(2)));
typedef float    floatx4 __attribute__((ext_vector_type(4)));

#define KNN 40
#define KVPAD 124

// ---------------- workspace layout (bytes) ----------------
#define WS_NF16    0ull
#define WS_EMB16   25600000ull
#define WS_WKVT    28672000ull
#define WS_WQ4     29065216ull   // 2 layers x 32768 B each
#define WS_W1A4    29196288ull
#define WS_W1B4    29327360ull
#define WS_W24     29458432ull
#define WS_QBIAS   29589504ull
#define WS_WOFTMP  29590528ull
#define WS_ZERO    29721600ull
#define WS_EF16    29721856ull
#define WS_TOTAL_FULL (WS_EF16 + 128000000ull)

// global -> LDS direct copy, 16 B per lane, dest = wave-uniform base + lane*16
__device__ __forceinline__ void ld16(const void* g, void* l) {
  __builtin_amdgcn_global_load_lds(
      (const __attribute__((address_space(1))) unsigned int*)(uintptr_t)g,
      (__attribute__((address_space(3))) unsigned int*)(uintptr_t)l, 16, 0, 0);
}

__device__ __forceinline__ float dot8(half8 a, half8 b, float s) {
  s = __builtin_amdgcn_fdot2((h2f){a[0], a[1]}, (h2f){b[0], b[1]}, s, false);
  s = __builtin_amdgcn_fdot2((h2f){a[2], a[3]}, (h2f){b[2], b[3]}, s, false);
  s = __builtin_amdgcn_fdot2((h2f){a[4], a[5]}, (h2f){b[4], b[5]}, s, false);
  s = __builtin_amdgcn_fdot2((h2f){a[6], a[7]}, (h2f){b[6], b[7]}, s, false);
  return s;
}

// ---------------------------------------------------------------------------
__global__ __launch_bounds__(256) void cvt_kernel(
    const float* __restrict__ src, half_t* __restrict__ dst, int n8) {
  int stride = gridDim.x * 256;
  for (int i = blockIdx.x * 256 + threadIdx.x; i < n8; i += stride) {
    float4 a = *((const float4*)src + 2 * (size_t)i);
    float4 b = *((const float4*)src + 2 * (size_t)i + 1);
    half8 h;
    h[0] = (half_t)a.x; h[1] = (half_t)a.y; h[2] = (half_t)a.z; h[3] = (half_t)a.w;
    h[4] = (half_t)b.x; h[5] = (half_t)b.y; h[6] = (half_t)b.z; h[7] = (half_t)b.w;
    *((half8*)dst + i) = h;
  }
}

// decode t -> (l, d8, j, e) for the 8-row-pack (MFMA b-frag) layout:
// idx = l*16384 + (d8*128 + j)*8 + e  holds  W[k = 8*d8 + e][col = j]
#define PK8_DECODE(t) int l = (t) >> 14; int u = (t) & 16383; \
  int d8 = u >> 10; int v = u & 1023; int j = v >> 3; int e = v & 7;

__global__ __launch_bounds__(256) void precompute_w(
    const float* __restrict__ Wq, const float* __restrict__ Wk,
    const float* __restrict__ Wv, const float* __restrict__ Wo,
    const float* __restrict__ fc1, const float* __restrict__ fc2,
    const float* __restrict__ time_b,
    half_t* __restrict__ WkvT, float* __restrict__ qbias,
    float* __restrict__ woftmp, half_t* __restrict__ Wq4,
    half_t* __restrict__ W1b4, half_t* __restrict__ W24,
    half_t* __restrict__ zrow)
{
  int blk = blockIdx.x, tid = threadIdx.x;
  if (blk < 768) {
    int t = blk * 256 + tid;            // [0, 2*256*384)
    int l = t / 98304;
    int r = t - l * 98304;
    int n = r / 384;
    int k = r - n * 384;
    float vv = (n < 128) ? Wk[l * 49152 + k * 128 + n]
                         : Wv[l * 49152 + k * 128 + (n - 128)];
    WkvT[t] = (half_t)vv;
  } else if (blk == 768) {
    if (tid < 128) zrow[tid] = (half_t)0.f;
    int l = tid >> 7, j = tid & 127;
    float s = 0.f;
    for (int d = 0; d < 128; ++d)
      s += cosf(time_b[d]) * Wq[l * 32768 + (128 + d) * 128 + j];
    qbias[l * 128 + j] = s;
  } else if (blk < 897) {
    int t = (blk - 769) * 256 + tid;    // Wofc1 = Wo @ fc1_top (f32 temp)
    int l = t >> 14;
    int r = t & 16383;
    int dd = r >> 7, j = r & 127;
    float s = 0.f;
    for (int m = 0; m < 128; ++m)
      s += Wo[l * 16384 + dd * 128 + m] * fc1[l * 32768 + m * 128 + j];
    woftmp[t] = s;
  } else if (blk < 1025) {
    int t = (blk - 897) * 256 + tid;
    PK8_DECODE(t);
    Wq4[t] = (half_t)Wq[l * 32768 + (8 * d8 + e) * 128 + j];
  } else if (blk < 1153) {
    int t = (blk - 1025) * 256 + tid;
    PK8_DECODE(t);
    W1b4[t] = (half_t)fc1[l * 32768 + (128 + 8 * d8 + e) * 128 + j];
  } else {
    int t = (blk - 1153) * 256 + tid;
    PK8_DECODE(t);
    W24[t] = (half_t)fc2[l * 16384 + (8 * d8 + e) * 128 + j];
  }
}

__global__ __launch_bounds__(256) void precompute_w2(
    const float* __restrict__ woftmp, half_t* __restrict__ W1a4) {
  int t = blockIdx.x * 256 + threadIdx.x;
  PK8_DECODE(t);
  W1a4[t] = (half_t)woftmp[l * 16384 + (8 * d8 + e) * 128 + j];
}

// ---------------------------------------------------------------------------
// Fused hop aggregation. 512 thr = 8 waves, 3 batches/block (120 kv rows).
// v3: epilogue de-LDS-ified. FFN (h1 = relu(aO*W1a + src*W1b); out = h1*W24)
// runs as MFMA on waves 0-3 with B-fragments read directly from global
// (L2-hot 8-pack layout) -- no weight staging to LDS at all. attnOut and
// scores phases vectorized. K-loop pipeline (counted vmcnt) unchanged.
// ---------------------------------------------------------------------------
template <bool EF16, bool L1DIR>
__global__ __launch_bounds__(512, 4) void hop_kernel(
    const float*  __restrict__ nf,
    const half_t* __restrict__ ne16,     // L0: nf16 (gather via neigh); L1: emb116 direct
    const half_t* __restrict__ ef16,
    const float*  __restrict__ ef32,
    const int*    __restrict__ src_idx,
    const float*  __restrict__ tsv,
    const int*    __restrict__ neigh,
    const int*    __restrict__ eidx,
    const float*  __restrict__ etimes,
    const float*  __restrict__ tw,
    const float*  __restrict__ tb,
    const half_t* __restrict__ Wq4_l,
    const float*  __restrict__ qbias_l,
    const half_t* __restrict__ WkvT_l,
    const half_t* __restrict__ W1a4_l,
    const half_t* __restrict__ W1b4_l,
    const half_t* __restrict__ W24_l,
    const half_t* __restrict__ zrow,
    half_t* __restrict__ out16,
    float*  __restrict__ out32)
{
  // LDS: A bufs 4x8K @0, B bufs 2x16K @32768, persists @65536
  __shared__ __align__(16) char smem[71360];
  half_t* BTs  = (half_t*)(smem + 32768);
  half_t* kvT  = (half_t*)(smem + 32768);
  float*  tw_s = (float*)(smem + 65536);
  float*  tb_s = (float*)(smem + 66048);
  float*  qs   = (float*)(smem + 66560);
  half_t* s16  = (half_t*)(smem + 68096);
  half_t* aO16 = (half_t*)(smem + 68864);
  half_t* h116 = (half_t*)(smem + 69632);
  float*  scs  = (float*)(smem + 70400);

  const int tid = threadIdx.x;
  const int bbase = blockIdx.x * 3;
  const int lane = tid & 63, wv = tid >> 6;
  const int l15 = lane & 15, q4 = lane >> 4;
  const int wm = (wv & 1) * 64, wn = (wv >> 1) * 64;

  // ---- setup ----
  if (tid < 128) { tw_s[tid] = tw[tid]; tb_s[tid] = tb[tid]; }
  if (tid < 96) {
    int g = tid >> 5, d4 = tid & 31;
    float4 v4 = *(const float4*)(nf + (size_t)src_idx[bbase + g] * 128 + d4 * 4);
    half4_t h;
    h[0] = (half_t)v4.x; h[1] = (half_t)v4.y; h[2] = (half_t)v4.z; h[3] = (half_t)v4.w;
    *(half4_t*)(s16 + g * 128 + d4 * 4) = h;
  }

  // preload the score mask so the scores phase has no global load in it
  int neighval = 1;
  if (tid < 240) {
    int g = tid / 80, rem = tid - g * 80, n = rem % 40;
    neighval = neigh[(bbase + g) * KNN + n];
  }

  // per-lane A-row setup (row r = wv*16 + l15, folded q4*8 column offset)
  const int r = wv * 16 + l15;
  const bool valid = (r < 120);
  float dval = 0.f;
  const half_t* pNE = zrow + q4 * 8;
  const half_t* pEF = zrow + q4 * 8;
  if (valid) {
    int g = r / 40, n = r - g * 40;
    int bg = bbase + g;
    int rowidx = bg * KNN + n;
    dval = tsv[L1DIR ? bg : (bg / 40)] - etimes[rowidx];
    pNE = (L1DIR ? ne16 + (size_t)rowidx * 128
                 : ne16 + (size_t)neigh[rowidx] * 128) + q4 * 8;
    if (EF16) pEF = ef16 + (size_t)eidx[rowidx] * 128 + q4 * 8;
  }
  // fallback EF(f32) per-thread setup (4 threads/row, 8 floats each per step)
  const float* gbe32 = nullptr;
  const int rr = tid >> 2, pp = tid & 3;
  if (!EF16 && rr < 120) {
    int g2 = rr / 40, n2 = rr - g2 * 40;
    gbe32 = ef32 + (size_t)eidx[(bbase + g2) * KNN + n2] * 128 + pp * 8;
  }

  // B per-lane source base (f16 elems); WkvT is [n(256)][k(384)]
  const half_t* bBase = WkvT_l + (size_t)(2 * wv * 16 + l15) * 384 + q4 * 8;

  floatx4 acc[4][4];
  #pragma unroll
  for (int mi = 0; mi < 4; ++mi)
    #pragma unroll
    for (int ni = 0; ni < 4; ++ni) acc[mi][ni] = (floatx4){0.f, 0.f, 0.f, 0.f};

  // step s -> weight k-chunk: ne s<4 -> s ; ef 4..7 -> s+4 ; et 8..11 -> s-4
  auto issB = [&](int s, char* bb) {
    int kc = (s < 4) ? s : (s < 8 ? s + 4 : s - 4);
    const half_t* bp = bBase + kc * 32;
    ld16(bp,        bb + wv * 2048);          // colgroup 2wv
    ld16(bp + 6144, bb + wv * 2048 + 1024);   // colgroup 2wv+1
  };
  auto issA = [&](int s, char* ab) {          // s in 0..7 (gather steps)
    const half_t* p = (s < 4) ? pNE + s * 32 : pEF + (s - 4) * 32;
    ld16(p, ab + wv * 1024);
  };
  auto cosA = [&](int s, char* ab) {          // s in 8..11 (time-encoding)
    int cb = (s - 8) * 32 + q4 * 8;
    half8 h;
    #pragma unroll
    for (int j = 0; j < 8; ++j) {
      float ang = __builtin_fmaf(dval, tw_s[cb + j], tb_s[cb + j]);
      h[j] = valid ? (half_t)__cosf(ang) : (half_t)0.f;
    }
    *(half8*)(ab + wv * 1024 + lane * 16) = h;
  };
  auto efA32 = [&](int s, char* ab) {         // fallback f32 edge feats
    half8 h = {};
    if (rr < 120) {
      const float* gb = gbe32 + (s - 4) * 32;
      float4 v0 = ((const float4*)gb)[0];
      float4 v1 = ((const float4*)gb)[1];
      h[0] = (half_t)v0.x; h[1] = (half_t)v0.y; h[2] = (half_t)v0.z; h[3] = (half_t)v0.w;
      h[4] = (half_t)v1.x; h[5] = (half_t)v1.y; h[6] = (half_t)v1.z; h[7] = (half_t)v1.w;
    }
    *(half8*)(ab + (rr >> 4) * 1024 + pp * 256 + (rr & 15) * 16) = h;
  };
  auto mfma_step = [&](const char* ab, const char* bb) {
    const half_t* A  = (const half_t*)ab;
    const half_t* Bp = (const half_t*)bb;
    half8 a[4];
    #pragma unroll
    for (int mi = 0; mi < 4; ++mi)
      a[mi] = *(const half8*)(A + ((wv & 1) * 4 + mi) * 512 + q4 * 128 + l15 * 8);
    #pragma unroll
    for (int ni = 0; ni < 4; ++ni) {
      half8 bfr = *(const half8*)(Bp + (((wn >> 4) + ni) * 512) + q4 * 128 + l15 * 8);
      #pragma unroll
      for (int mi = 0; mi < 4; ++mi)
        acc[mi][ni] = __builtin_amdgcn_mfma_f32_16x16x32_f16(a[mi], bfr, acc[mi][ni], 0, 0, 0);
    }
  };

#define AB(i) (smem + (i) * 8192)
#define BB(i) (smem + 32768 + (i) * 16384)
#define FENCE asm volatile("" ::: "memory")

  // ---- prologue: issue B0,B1 + all 4 ne A-chunks; sync setup LDS only ----
  FENCE;
  issB(0, BB(0)); issB(1, BB(1));
  issA(0, AB(0)); issA(1, AB(1)); issA(2, AB(2)); issA(3, AB(3));
  asm volatile("s_waitcnt lgkmcnt(0)" ::: "memory");
  __builtin_amdgcn_s_barrier(); FENCE;

  // ---- K-loop: 12 steps, counted vmcnt (WE = EF16 counts, WF = f32-EF counts)
#define HSTEP(s, WE, WF, ...)                                                   \
  asm volatile("s_waitcnt vmcnt(%0) lgkmcnt(0)" :: "i"(EF16 ? (WE) : (WF))      \
               : "memory");                                                     \
  __builtin_amdgcn_s_barrier(); FENCE;                                          \
  mfma_step(AB((s) & 3), BB((s) & 1));                                          \
  FENCE; __builtin_amdgcn_s_barrier(); FENCE;                                   \
  __VA_ARGS__

  HSTEP(0, 3, 3, issB(2, BB(0)); if constexpr (EF16) issA(4, AB(0)); else efA32(4, AB(0));)
  HSTEP(1, 5, 4, issB(3, BB(1)); if constexpr (EF16) issA(5, AB(1)); else efA32(5, AB(1));)
  HSTEP(2, 7, 5, issB(4, BB(0)); if constexpr (EF16) issA(6, AB(2)); else efA32(6, AB(2));)
  HSTEP(3, 9, 6, issB(5, BB(1)); if constexpr (EF16) issA(7, AB(3)); else efA32(7, AB(3));)
  HSTEP(4, 4, 2, issB(6, BB(0)); cosA(8, AB(0));)
  HSTEP(5, 3, 2, issB(7, BB(1)); cosA(9, AB(1));)
  HSTEP(6, 2, 2, issB(8, BB(0)); cosA(10, AB(2));)
  HSTEP(7, 2, 2, issB(9, BB(1)); cosA(11, AB(3));)
  HSTEP(8, 2, 2, issB(10, BB(0));)
  HSTEP(9, 2, 2, issB(11, BB(1));)
  HSTEP(10, 2, 2, )
  HSTEP(11, 0, 0, )
#undef HSTEP

  // ---- epilogue (global_load_lds queue empty from here on) ----

  // kk -> kvT (cols 0..127)
  if (wv < 4) {
    #pragma unroll
    for (int mi = 0; mi < 4; ++mi) {
      int row0 = wm + mi * 16 + q4 * 4;
      if (row0 < 120) {
        #pragma unroll
        for (int ni = 0; ni < 4; ++ni) {
          int col = wn + ni * 16 + l15;
          half4_t h;
          h[0] = (half_t)acc[mi][ni][0]; h[1] = (half_t)acc[mi][ni][1];
          h[2] = (half_t)acc[mi][ni][2]; h[3] = (half_t)acc[mi][ni][3];
          *(half4_t*)(kvT + col * KVPAD + row0) = h;
        }
      }
    }
  }

  // q = src @ Wq_top + qbias (Wq4 8-pack read straight from L2, coalesced)
  if (tid < 384) {
    int gq = tid >> 7, jj = tid & 127;
    float s = qbias_l[jj];
    #pragma unroll
    for (int d8 = 0; d8 < 16; ++d8) {
      half8 w = *(const half8*)(Wq4_l + (d8 * 128 + jj) * 8);
      half8 a = *(const half8*)(s16 + gq * 128 + d8 * 8);
      s = dot8(w, a, s);
    }
    qs[gq * 128 + jj] = s;
  }
  asm volatile("s_waitcnt lgkmcnt(0)" ::: "memory");
  __builtin_amdgcn_s_barrier(); FENCE;   // E1: kvT + qs visible

  // ---- scores (mask preloaded; q read as float4 broadcasts) ----
  if (tid < 240) {
    int g = tid / 80;
    int rem = tid - g * 80;
    int hh = rem / 40;
    int n = rem - hh * 40;
    const float4* qrow4 = (const float4*)(qs + g * 128 + hh * 64);
    int row = g * 40 + n;
    float s = 0.f;
    #pragma unroll
    for (int d4 = 0; d4 < 16; ++d4) {
      float4 qv = qrow4[d4];
      const half_t* kp = kvT + (hh * 64 + d4 * 4) * KVPAD + row;
      s += qv.x * (float)kp[0];
      s += qv.y * (float)kp[KVPAD];
      s += qv.z * (float)kp[2 * KVPAD];
      s += qv.w * (float)kp[3 * KVPAD];
    }
    scs[tid] = (neighval == 0) ? -1e9f : s * 0.125f;
  }
  asm volatile("s_waitcnt lgkmcnt(0)" ::: "memory");
  __builtin_amdgcn_s_barrier(); FENCE;   // E2: scs visible

  // ---- softmax (waves 0..5) + vv -> kvT (waves 4..7) ----
  if (wv < 6) {
    float v = (lane < 40) ? scs[wv * 40 + lane] : -1e30f;
    float m = v;
    #pragma unroll
    for (int o = 32; o; o >>= 1) m = fmaxf(m, __shfl_xor(m, o));
    float e = (lane < 40) ? __expf(v - m) : 0.f;
    float ssum = e;
    #pragma unroll
    for (int o = 32; o; o >>= 1) ssum += __shfl_xor(ssum, o);
    if (lane < 40) scs[wv * 40 + lane] = e / ssum;
  }
  if (wv >= 4) {
    #pragma unroll
    for (int mi = 0; mi < 4; ++mi) {
      int row0 = wm + mi * 16 + q4 * 4;
      if (row0 < 120) {
        #pragma unroll
        for (int ni = 0; ni < 4; ++ni) {
          int col = wn - 128 + ni * 16 + l15;
          half4_t h;
          h[0] = (half_t)acc[mi][ni][0]; h[1] = (half_t)acc[mi][ni][1];
          h[2] = (half_t)acc[mi][ni][2]; h[3] = (half_t)acc[mi][ni][3];
          *(half4_t*)(kvT + col * KVPAD + row0) = h;
        }
      }
    }
  }
  asm volatile("s_waitcnt lgkmcnt(0)" ::: "memory");
  __builtin_amdgcn_s_barrier(); FENCE;   // E3: attn + vv visible

  // ---- attnOut -> aO16 (vectorized: half4 v, float4 attn broadcasts) ----
  if (tid < 384) {
    int g = tid >> 7, dcol = tid & 127, hh = dcol >> 6;
    const float4* at4 = (const float4*)(scs + (g * 2 + hh) * 40);
    const half_t* vcol = kvT + dcol * KVPAD + g * 40;
    float s = 0.f;
    #pragma unroll
    for (int n4 = 0; n4 < 10; ++n4) {
      float4 a4 = at4[n4];
      half4_t v = *(const half4_t*)(vcol + n4 * 4);
      s += a4.x * (float)v[0] + a4.y * (float)v[1]
         + a4.z * (float)v[2] + a4.w * (float)v[3];
    }
    aO16[g * 128 + dcol] = (half_t)s;
  }
  asm volatile("s_waitcnt lgkmcnt(0)" ::: "memory");
  __builtin_amdgcn_s_barrier(); FENCE;   // E4: aO16 visible; kvT dead

  // ---- FFN via MFMA on waves 0-3: h1 = relu(aO*W1a + src*W1b) ----
  // A-frag: lane(l15,q4) = A[row=l15][k=q4*8+e]; rows 3..15 clamped to row 0
  // (their acc rows are never read). B-frags from global 8-pack (L2-hot).
  {
    const int ar = (l15 < 3) ? l15 : 0;
    if (wv < 4) {
      const int ni0 = wv * 2;
      floatx4 facc0 = (floatx4){0.f, 0.f, 0.f, 0.f};
      floatx4 facc1 = (floatx4){0.f, 0.f, 0.f, 0.f};
      #pragma unroll
      for (int kc = 0; kc < 4; ++kc) {
        half8 a1 = *(const half8*)(aO16 + ar * 128 + kc * 32 + q4 * 8);
        half8 a2 = *(const half8*)(s16  + ar * 128 + kc * 32 + q4 * 8);
        int kb = (kc * 4 + q4) * 128;
        half8 b1a = *(const half8*)(W1a4_l + (size_t)(kb + ni0 * 16 + l15) * 8);
        half8 b1b = *(const half8*)(W1a4_l + (size_t)(kb + ni0 * 16 + 16 + l15) * 8);
        half8 b2a = *(const half8*)(W1b4_l + (size_t)(kb + ni0 * 16 + l15) * 8);
        half8 b2b = *(const half8*)(W1b4_l + (size_t)(kb + ni0 * 16 + 16 + l15) * 8);
        facc0 = __builtin_amdgcn_mfma_f32_16x16x32_f16(a1, b1a, facc0, 0, 0, 0);
        facc1 = __builtin_amdgcn_mfma_f32_16x16x32_f16(a1, b1b, facc1, 0, 0, 0);
        facc0 = __builtin_amdgcn_mfma_f32_16x16x32_f16(a2, b2a, facc0, 0, 0, 0);
        facc1 = __builtin_amdgcn_mfma_f32_16x16x32_f16(a2, b2b, facc1, 0, 0, 0);
      }
      // C layout: row = q4*4 + e, col = l15 -> rows 0..2 live in q4==0 lanes
      if (q4 == 0) {
        #pragma unroll
        for (int e = 0; e < 3; ++e) {
          h116[e * 128 + ni0 * 16 + l15]       = (half_t)fmaxf(facc0[e], 0.f);
          h116[e * 128 + (ni0 + 1) * 16 + l15] = (half_t)fmaxf(facc1[e], 0.f);
        }
      }
    }
  }
  asm volatile("s_waitcnt lgkmcnt(0)" ::: "memory");
  __builtin_amdgcn_s_barrier(); FENCE;   // E5: h116 visible

  // ---- fc2 via MFMA on waves 0-3; write out directly ----
  {
    const int ar = (l15 < 3) ? l15 : 0;
    if (wv < 4) {
      const int ni0 = wv * 2;
      floatx4 facc0 = (floatx4){0.f, 0.f, 0.f, 0.f};
      floatx4 facc1 = (floatx4){0.f, 0.f, 0.f, 0.f};
      #pragma unroll
      for (int kc = 0; kc < 4; ++kc) {
        half8 a = *(const half8*)(h116 + ar * 128 + kc * 32 + q4 * 8);
        int kb = (kc * 4 + q4) * 128;
        half8 ba = *(const half8*)(W24_l + (size_t)(kb + ni0 * 16 + l15) * 8);
        half8 bb = *(const half8*)(W24_l + (size_t)(kb + ni0 * 16 + 16 + l15) * 8);
        facc0 = __builtin_amdgcn_mfma_f32_16x16x32_f16(a, ba, facc0, 0, 0, 0);
        facc1 = __builtin_amdgcn_mfma_f32_16x16x32_f16(a, bb, facc1, 0, 0, 0);
      }
      if (q4 == 0) {
        #pragma unroll
        for (int e = 0; e < 3; ++e) {
          if (L1DIR) {
            out32[(size_t)(bbase + e) * 128 + ni0 * 16 + l15]       = facc0[e];
            out32[(size_t)(bbase + e) * 128 + (ni0 + 1) * 16 + l15] = facc1[e];
          } else {
            out16[(size_t)(bbase + e) * 128 + ni0 * 16 + l15]       = (half_t)facc0[e];
            out16[(size_t)(bbase + e) * 128 + (ni0 + 1) * 16 + l15] = (half_t)facc1[e];
          }
        }
      }
    }
  }
#undef AB
#undef BB
#undef FENCE
}

// ---------------------------------------------------------------------------
extern "C" void kernel_launch(void* const* d_in, const int* in_sizes, int n_in,
                              void* d_out, int out_size, void* d_ws, size_t ws_size,
                              hipStream_t stream) {
  const float* nf      = (const float*)d_in[0];
  const float* ef      = (const float*)d_in[1];
  const float* tw      = (const float*)d_in[2];
  const float* tb      = (const float*)d_in[3];
  const float* Wq      = (const float*)d_in[4];
  const float* Wk      = (const float*)d_in[5];
  const float* Wv      = (const float*)d_in[6];
  const float* Wo      = (const float*)d_in[7];
  const float* fc1     = (const float*)d_in[8];
  const float* fc2     = (const float*)d_in[9];
  const int*   srcn    = (const int*)d_in[10];
  const float* ts      = (const float*)d_in[11];
  const int*   neigh2  = (const int*)d_in[12];
  const int*   eidx2   = (const int*)d_in[13];
  const float* etimes2 = (const float*)d_in[14];
  const int*   neigh1  = (const int*)d_in[15];
  const int*   eidx1   = (const int*)d_in[16];
  const float* etimes1 = (const float*)d_in[17];

  char* ws = (char*)d_ws;
  half_t* nf16   = (half_t*)(ws + WS_NF16);
  half_t* emb116 = (half_t*)(ws + WS_EMB16);
  half_t* WkvT16 = (half_t*)(ws + WS_WKVT);
  half_t* Wq4    = (half_t*)(ws + WS_WQ4);
  half_t* W1a4   = (half_t*)(ws + WS_W1A4);
  half_t* W1b4   = (half_t*)(ws + WS_W1B4);
  half_t* W24    = (half_t*)(ws + WS_W24);
  float*  qbias  = (float*)(ws + WS_QBIAS);
  float*  woftmp = (float*)(ws + WS_WOFTMP);
  half_t* zrow   = (half_t*)(ws + WS_ZERO);
  half_t* ef16   = (half_t*)(ws + WS_EF16);

  bool full = (ws_size >= WS_TOTAL_FULL);

  cvt_kernel<<<dim3(2048), dim3(256), 0, stream>>>(nf, nf16, 1600000);
  if (full)
    cvt_kernel<<<dim3(4096), dim3(256), 0, stream>>>(ef, ef16, 8000000);
  precompute_w<<<dim3(1281), dim3(256), 0, stream>>>(
      Wq, Wk, Wv, Wo, fc1, fc2, tb, WkvT16, qbias, woftmp, Wq4, W1b4, W24, zrow);
  precompute_w2<<<dim3(128), dim3(256), 0, stream>>>(woftmp, W1a4);

  if (full) {
    hop_kernel<true, false><<<dim3(4000), dim3(512), 0, stream>>>(
        nf, nf16, ef16, ef, neigh2, ts, neigh1, eidx1, etimes1, tw, tb,
        Wq4, qbias, WkvT16, W1a4, W1b4, W24, zrow, emb116, nullptr);
    hop_kernel<true, true><<<dim3(100), dim3(512), 0, stream>>>(
        nf, emb116, ef16, ef, srcn, ts, neigh2, eidx2, etimes2, tw, tb,
        Wq4 + 16384, qbias + 128, WkvT16 + 98304, W1a4 + 16384, W1b4 + 16384,
        W24 + 16384, zrow, emb116, (float*)d_out);
  } else {
    hop_kernel<false, false><<<dim3(4000), dim3(512), 0, stream>>>(
        nf, nf16, ef16, ef, neigh2, ts, neigh1, eidx1, etimes1, tw, tb,
        Wq4, qbias, WkvT16, W1a4, W1b4, W24, zrow, emb116, nullptr);
    hop_kernel<false, true><<<dim3(100), dim3(512), 0, stream>>>(
        nf, emb116, ef16, ef, srcn, ts, neigh2, eidx2, etimes2, tw, tb,
        Wq4 + 16384, qbias + 128, WkvT16 + 98304, W1a4 + 16384, W1b4 + 16384,
        W24 + 16384, zrow, emb116, (float*)d_out);
  }
}

// Round 6
// 673.177 us; speedup vs baseline: 1.0900x; 1.0223x over previous
//
#include <hip/hip_runtime.h>
#include <cstdint>

typedef _Float16 half_t;
typedef _Float16 half8  __attribute__((ext_vector_type(8)));
typedef _Float16 half4_t __attribute__((ext_vector_type(4)));
typedef _Float16 h2f    __attribute__((ext_vector_type(2)));
typedef float    floatx4 __attribute__((ext_vector_type(4)));

#define KNN 40
#define KVPAD 124

// ---------------- workspace layout (bytes) ----------------
#define WS_NF16    0ull
#define WS_EMB16   25600000ull
#define WS_WKVT    28672000ull
#define WS_WQ4     29065216ull   // 2 layers x 32768 B each
#define WS_W1A4    29196288ull
#define WS_W1B4    29327360ull
#define WS_W24     29458432ull
#define WS_QBIAS   29589504ull
#define WS_WOFTMP  29590528ull
#define WS_ZERO    29721600ull
#define WS_EF16    29721856ull
#define WS_TOTAL_FULL (WS_EF16 + 128000000ull)

// global -> LDS direct copy, 16 B per lane, dest = wave-uniform base + lane*16
__device__ __forceinline__ void ld16(const void* g, void* l) {
  __builtin_amdgcn_global_load_lds(
      (const __attribute__((address_space(1))) unsigned int*)(uintptr_t)g,
      (__attribute__((address_space(3))) unsigned int*)(uintptr_t)l, 16, 0, 0);
}

__device__ __forceinline__ float dot8(half8 a, half8 b, float s) {
  s = __builtin_amdgcn_fdot2((h2f){a[0], a[1]}, (h2f){b[0], b[1]}, s, false);
  s = __builtin_amdgcn_fdot2((h2f){a[2], a[3]}, (h2f){b[2], b[3]}, s, false);
  s = __builtin_amdgcn_fdot2((h2f){a[4], a[5]}, (h2f){b[4], b[5]}, s, false);
  s = __builtin_amdgcn_fdot2((h2f){a[6], a[7]}, (h2f){b[6], b[7]}, s, false);
  return s;
}

// ---------------------------------------------------------------------------
__global__ __launch_bounds__(256) void cvt_kernel(
    const float* __restrict__ src, half_t* __restrict__ dst, int n8) {
  int stride = gridDim.x * 256;
  for (int i = blockIdx.x * 256 + threadIdx.x; i < n8; i += stride) {
    float4 a = *((const float4*)src + 2 * (size_t)i);
    float4 b = *((const float4*)src + 2 * (size_t)i + 1);
    half8 h;
    h[0] = (half_t)a.x; h[1] = (half_t)a.y; h[2] = (half_t)a.z; h[3] = (half_t)a.w;
    h[4] = (half_t)b.x; h[5] = (half_t)b.y; h[6] = (half_t)b.z; h[7] = (half_t)b.w;
    *((half8*)dst + i) = h;
  }
}

// decode t -> (l, d8, j, e) for the 8-row-pack (MFMA b-frag) layout:
// idx = l*16384 + (d8*128 + j)*8 + e  holds  W[k = 8*d8 + e][col = j]
#define PK8_DECODE(t) int l = (t) >> 14; int u = (t) & 16383; \
  int d8 = u >> 10; int v = u & 1023; int j = v >> 3; int e = v & 7;

__global__ __launch_bounds__(256) void precompute_w(
    const float* __restrict__ Wq, const float* __restrict__ Wk,
    const float* __restrict__ Wv, const float* __restrict__ Wo,
    const float* __restrict__ fc1, const float* __restrict__ fc2,
    const float* __restrict__ time_b,
    half_t* __restrict__ WkvT, float* __restrict__ qbias,
    float* __restrict__ woftmp, half_t* __restrict__ Wq4,
    half_t* __restrict__ W1b4, half_t* __restrict__ W24,
    half_t* __restrict__ zrow)
{
  int blk = blockIdx.x, tid = threadIdx.x;
  if (blk < 768) {
    // WkvT pack in exact issB streaming order so each wave's per-step B load
    // is a contiguous 1KB: halfs idx = l*98304 + kc*8192 + cg*512 + ln*8 + e
    // holds W[k = kc*32 + (ln>>4)*8 + e][n = cg*16 + (ln&15)]
    int t = blk * 256 + tid;            // [0, 196608)
    int l = t / 98304;
    int r = t - l * 98304;
    int kc  = r >> 13;
    int r2  = r & 8191;
    int cg  = r2 >> 9;
    int r4  = r2 & 511;
    int ln  = r4 >> 3;
    int e   = r4 & 7;
    int n   = cg * 16 + (ln & 15);
    int k   = kc * 32 + (ln >> 4) * 8 + e;
    float vv = (n < 128) ? Wk[l * 49152 + k * 128 + n]
                         : Wv[l * 49152 + k * 128 + (n - 128)];
    WkvT[t] = (half_t)vv;
  } else if (blk == 768) {
    if (tid < 128) zrow[tid] = (half_t)0.f;
    int l = tid >> 7, j = tid & 127;
    float s = 0.f;
    for (int d = 0; d < 128; ++d)
      s += cosf(time_b[d]) * Wq[l * 32768 + (128 + d) * 128 + j];
    qbias[l * 128 + j] = s;
  } else if (blk < 897) {
    int t = (blk - 769) * 256 + tid;    // Wofc1 = Wo @ fc1_top (f32 temp)
    int l = t >> 14;
    int r = t & 16383;
    int dd = r >> 7, j = r & 127;
    float s = 0.f;
    for (int m = 0; m < 128; ++m)
      s += Wo[l * 16384 + dd * 128 + m] * fc1[l * 32768 + m * 128 + j];
    woftmp[t] = s;
  } else if (blk < 1025) {
    int t = (blk - 897) * 256 + tid;
    PK8_DECODE(t);
    Wq4[t] = (half_t)Wq[l * 32768 + (8 * d8 + e) * 128 + j];
  } else if (blk < 1153) {
    int t = (blk - 1025) * 256 + tid;
    PK8_DECODE(t);
    W1b4[t] = (half_t)fc1[l * 32768 + (128 + 8 * d8 + e) * 128 + j];
  } else {
    int t = (blk - 1153) * 256 + tid;
    PK8_DECODE(t);
    W24[t] = (half_t)fc2[l * 16384 + (8 * d8 + e) * 128 + j];
  }
}

__global__ __launch_bounds__(256) void precompute_w2(
    const float* __restrict__ woftmp, half_t* __restrict__ W1a4) {
  int t = blockIdx.x * 256 + threadIdx.x;
  PK8_DECODE(t);
  W1a4[t] = (half_t)woftmp[l * 16384 + (8 * d8 + e) * 128 + j];
}

// ---------------------------------------------------------------------------
// Fused hop aggregation. 512 thr = 8 waves, 3 batches/block (120 kv rows).
// v6 = v5 with the vmcnt schedule race FIXED. FIFO derivation:
//   P: B0,B0,B1,B1,A0,A1,A2,A3 | S0e: B2,B2,A4 | S1e: B3,B3,A5 | S2e: B4,B4,A6
//   | S3e: B5,B5,A7 | S4e..S9e: Bs,Bs | S10e,S11e: -
// Step s needs A(s) and B(s) confirmed; B(s) is LATER in the queue (issued at
// end of s-2). Correct WE: S0=3,S1=5,S2=4,S3=4,S4=4,S5=3,S6..S10=2,S11=0.
// (v2-v5 had S2=7,S3=9 -- B2/B3 read unconfirmed; latent race.)
// EF32: ef loads are compiler-drained before their LDS writes -> WF S2=S3=2.
// ---------------------------------------------------------------------------
template <bool EF16, bool L1DIR>
__global__ __launch_bounds__(512, 4) void hop_kernel(
    const float*  __restrict__ nf,
    const half_t* __restrict__ ne16,     // L0: nf16 (gather via neigh); L1: emb116 direct
    const half_t* __restrict__ ef16,
    const float*  __restrict__ ef32,
    const int*    __restrict__ src_idx,
    const float*  __restrict__ tsv,
    const int*    __restrict__ neigh,
    const int*    __restrict__ eidx,
    const float*  __restrict__ etimes,
    const float*  __restrict__ tw,
    const float*  __restrict__ tb,
    const half_t* __restrict__ Wq4_l,
    const float*  __restrict__ qbias_l,
    const half_t* __restrict__ WkvT_l,
    const half_t* __restrict__ W1a4_l,
    const half_t* __restrict__ W1b4_l,
    const half_t* __restrict__ W24_l,
    const half_t* __restrict__ zrow,
    half_t* __restrict__ out16,
    float*  __restrict__ out32)
{
  // LDS: A bufs 4x8K @0, B bufs 2x16K @32768, persists @65536
  __shared__ __align__(16) char smem[71360];
  half_t* kvT  = (half_t*)(smem + 32768);
  float*  tw_s = (float*)(smem + 65536);
  float*  tb_s = (float*)(smem + 66048);
  float*  qs   = (float*)(smem + 66560);
  half_t* s16  = (half_t*)(smem + 68096);
  half_t* aO16 = (half_t*)(smem + 68864);
  half_t* h116 = (half_t*)(smem + 69632);
  float*  scs  = (float*)(smem + 70400);

  const int tid = threadIdx.x;
  const int bbase = blockIdx.x * 3;
  const int lane = tid & 63, wv = tid >> 6;
  const int l15 = lane & 15, q4 = lane >> 4;
  const int wm = (wv & 1) * 64, wn = (wv >> 1) * 64;

  // ---- setup ----
  if (tid < 128) { tw_s[tid] = tw[tid]; tb_s[tid] = tb[tid]; }
  if (tid < 96) {
    int g = tid >> 5, d4 = tid & 31;
    float4 v4 = *(const float4*)(nf + (size_t)src_idx[bbase + g] * 128 + d4 * 4);
    half4_t h;
    h[0] = (half_t)v4.x; h[1] = (half_t)v4.y; h[2] = (half_t)v4.z; h[3] = (half_t)v4.w;
    *(half4_t*)(s16 + g * 128 + d4 * 4) = h;
  }

  // preload the score mask so the scores phase has no global load in it
  int neighval = 1;
  if (tid < 240) {
    int g = tid / 80, rem = tid - g * 80, n = rem % 40;
    neighval = neigh[(bbase + g) * KNN + n];
  }

  // per-lane A-row setup (row r = wv*16 + l15, folded q4*8 column offset)
  const int r = wv * 16 + l15;
  const bool valid = (r < 120);
  float dval = 0.f;
  const half_t* pNE = zrow + q4 * 8;
  const half_t* pEF = zrow + q4 * 8;
  if (valid) {
    int g = r / 40, n = r - g * 40;
    int bg = bbase + g;
    int rowidx = bg * KNN + n;
    dval = tsv[L1DIR ? bg : (bg / 40)] - etimes[rowidx];
    pNE = (L1DIR ? ne16 + (size_t)rowidx * 128
                 : ne16 + (size_t)neigh[rowidx] * 128) + q4 * 8;
    if (EF16) pEF = ef16 + (size_t)eidx[rowidx] * 128 + q4 * 8;
  }
  // fallback EF(f32) per-thread setup (4 threads/row, 8 floats each per step)
  const float* gbe32 = nullptr;
  const int rr = tid >> 2, pp = tid & 3;
  if (!EF16 && rr < 120) {
    int g2 = rr / 40, n2 = rr - g2 * 40;
    gbe32 = ef32 + (size_t)eidx[(bbase + g2) * KNN + n2] * 128 + pp * 8;
  }

  // B per-lane source base into the fragment-stream pack (halfs)
  const half_t* bpBase = WkvT_l + wv * 1024 + (size_t)lane * 8;

  floatx4 acc[4][4];
  #pragma unroll
  for (int mi = 0; mi < 4; ++mi)
    #pragma unroll
    for (int ni = 0; ni < 4; ++ni) acc[mi][ni] = (floatx4){0.f, 0.f, 0.f, 0.f};

  // step s -> weight k-chunk: ne s<4 -> s ; ef 4..7 -> s+4 ; et 8..11 -> s-4
  auto issB = [&](int s, char* bb) {
    int kc = (s < 4) ? s : (s < 8 ? s + 4 : s - 4);
    const half_t* bp = bpBase + kc * 8192;
    ld16(bp,       bb + wv * 2048);           // contiguous 1KB per wave
    ld16(bp + 512, bb + wv * 2048 + 1024);    // next contiguous 1KB
  };
  auto issA = [&](int s, char* ab) {          // s in 0..7 (gather steps)
    const half_t* p = (s < 4) ? pNE + s * 32 : pEF + (s - 4) * 32;
    ld16(p, ab + wv * 1024);
  };
  auto cosA = [&](int s, char* ab) {          // s in 8..11 (time-encoding)
    int cb = (s - 8) * 32 + q4 * 8;
    half8 h;
    #pragma unroll
    for (int j = 0; j < 8; ++j) {
      float ang = __builtin_fmaf(dval, tw_s[cb + j], tb_s[cb + j]);
      h[j] = valid ? (half_t)__cosf(ang) : (half_t)0.f;
    }
    *(half8*)(ab + wv * 1024 + lane * 16) = h;
  };
  auto efA32 = [&](int s, char* ab) {         // fallback f32 edge feats
    half8 h = {};
    if (rr < 120) {
      const float* gb = gbe32 + (s - 4) * 32;
      float4 v0 = ((const float4*)gb)[0];
      float4 v1 = ((const float4*)gb)[1];
      h[0] = (half_t)v0.x; h[1] = (half_t)v0.y; h[2] = (half_t)v0.z; h[3] = (half_t)v0.w;
      h[4] = (half_t)v1.x; h[5] = (half_t)v1.y; h[6] = (half_t)v1.z; h[7] = (half_t)v1.w;
    }
    *(half8*)(ab + (rr >> 4) * 1024 + pp * 256 + (rr & 15) * 16) = h;
  };
  auto mfma_step = [&](const char* ab, const char* bb) {
    const half_t* A  = (const half_t*)ab;
    const half_t* Bp = (const half_t*)bb;
    __builtin_amdgcn_s_setprio(1);
    half8 a[4];
    #pragma unroll
    for (int mi = 0; mi < 4; ++mi)
      a[mi] = *(const half8*)(A + ((wv & 1) * 4 + mi) * 512 + q4 * 128 + l15 * 8);
    #pragma unroll
    for (int ni = 0; ni < 4; ++ni) {
      half8 bfr = *(const half8*)(Bp + (((wn >> 4) + ni) * 512) + q4 * 128 + l15 * 8);
      #pragma unroll
      for (int mi = 0; mi < 4; ++mi)
        acc[mi][ni] = __builtin_amdgcn_mfma_f32_16x16x32_f16(a[mi], bfr, acc[mi][ni], 0, 0, 0);
    }
    __builtin_amdgcn_s_setprio(0);
  };

#define AB(i) (smem + (i) * 8192)
#define BB(i) (smem + 32768 + (i) * 16384)
#define FENCE asm volatile("" ::: "memory")

  // ---- prologue: issue B0,B1 + all 4 ne A-chunks; sync setup LDS only ----
  FENCE;
  issB(0, BB(0)); issB(1, BB(1));
  issA(0, AB(0)); issA(1, AB(1)); issA(2, AB(2)); issA(3, AB(3));
  asm volatile("s_waitcnt lgkmcnt(0)" ::: "memory");
  __builtin_amdgcn_s_barrier(); FENCE;

  // ---- K-loop: 12 steps, counted vmcnt (WE = EF16 counts, WF = f32-EF counts)
#define HSTEP(s, WE, WF, ...)                                                   \
  asm volatile("s_waitcnt vmcnt(%0) lgkmcnt(0)" :: "i"(EF16 ? (WE) : (WF))      \
               : "memory");                                                     \
  __builtin_amdgcn_s_barrier(); FENCE;                                          \
  mfma_step(AB((s) & 3), BB((s) & 1));                                          \
  FENCE; __builtin_amdgcn_s_barrier(); FENCE;                                   \
  __VA_ARGS__

  HSTEP(0, 3, 3, issB(2, BB(0)); if constexpr (EF16) issA(4, AB(0)); else efA32(4, AB(0));)
  HSTEP(1, 5, 4, issB(3, BB(1)); if constexpr (EF16) issA(5, AB(1)); else efA32(5, AB(1));)
  HSTEP(2, 4, 2, issB(4, BB(0)); if constexpr (EF16) issA(6, AB(2)); else efA32(6, AB(2));)
  HSTEP(3, 4, 2, issB(5, BB(1)); if constexpr (EF16) issA(7, AB(3)); else efA32(7, AB(3));)
  HSTEP(4, 4, 2, issB(6, BB(0)); cosA(8, AB(0));)
  HSTEP(5, 3, 2, issB(7, BB(1)); cosA(9, AB(1));)
  HSTEP(6, 2, 2, issB(8, BB(0)); cosA(10, AB(2));)
  HSTEP(7, 2, 2, issB(9, BB(1)); cosA(11, AB(3));)
  HSTEP(8, 2, 2, issB(10, BB(0));)
  HSTEP(9, 2, 2, issB(11, BB(1));)
  HSTEP(10, 2, 2, )
  HSTEP(11, 0, 0, )
#undef HSTEP

  // ---- epilogue (global_load_lds queue empty from here on) ----

  // kk -> kvT (cols 0..127)
  if (wv < 4) {
    #pragma unroll
    for (int mi = 0; mi < 4; ++mi) {
      int row0 = wm + mi * 16 + q4 * 4;
      if (row0 < 120) {
        #pragma unroll
        for (int ni = 0; ni < 4; ++ni) {
          int col = wn + ni * 16 + l15;
          half4_t h;
          h[0] = (half_t)acc[mi][ni][0]; h[1] = (half_t)acc[mi][ni][1];
          h[2] = (half_t)acc[mi][ni][2]; h[3] = (half_t)acc[mi][ni][3];
          *(half4_t*)(kvT + col * KVPAD + row0) = h;
        }
      }
    }
  }

  // q = src @ Wq_top + qbias (Wq4 8-pack read straight from L2, coalesced)
  if (tid < 384) {
    int gq = tid >> 7, jj = tid & 127;
    float s = qbias_l[jj];
    #pragma unroll
    for (int d8 = 0; d8 < 16; ++d8) {
      half8 w = *(const half8*)(Wq4_l + (d8 * 128 + jj) * 8);
      half8 a = *(const half8*)(s16 + gq * 128 + d8 * 8);
      s = dot8(w, a, s);
    }
    qs[gq * 128 + jj] = s;
  }
  asm volatile("s_waitcnt lgkmcnt(0)" ::: "memory");
  __builtin_amdgcn_s_barrier(); FENCE;   // E1: kvT + qs visible

  // ---- scores (mask preloaded; q read as float4 broadcasts) ----
  if (tid < 240) {
    int g = tid / 80;
    int rem = tid - g * 80;
    int hh = rem / 40;
    int n = rem - hh * 40;
    const float4* qrow4 = (const float4*)(qs + g * 128 + hh * 64);
    int row = g * 40 + n;
    float s = 0.f;
    #pragma unroll
    for (int d4 = 0; d4 < 16; ++d4) {
      float4 qv = qrow4[d4];
      const half_t* kp = kvT + (hh * 64 + d4 * 4) * KVPAD + row;
      s += qv.x * (float)kp[0];
      s += qv.y * (float)kp[KVPAD];
      s += qv.z * (float)kp[2 * KVPAD];
      s += qv.w * (float)kp[3 * KVPAD];
    }
    scs[tid] = (neighval == 0) ? -1e9f : s * 0.125f;
  }
  asm volatile("s_waitcnt lgkmcnt(0)" ::: "memory");
  __builtin_amdgcn_s_barrier(); FENCE;   // E2: scs visible

  // ---- softmax (waves 0..5) + vv -> kvT (waves 4..7) ----
  if (wv < 6) {
    float v = (lane < 40) ? scs[wv * 40 + lane] : -1e30f;
    float m = v;
    #pragma unroll
    for (int o = 32; o; o >>= 1) m = fmaxf(m, __shfl_xor(m, o));
    float e = (lane < 40) ? __expf(v - m) : 0.f;
    float ssum = e;
    #pragma unroll
    for (int o = 32; o; o >>= 1) ssum += __shfl_xor(ssum, o);
    if (lane < 40) scs[wv * 40 + lane] = e / ssum;
  }
  if (wv >= 4) {
    #pragma unroll
    for (int mi = 0; mi < 4; ++mi) {
      int row0 = wm + mi * 16 + q4 * 4;
      if (row0 < 120) {
        #pragma unroll
        for (int ni = 0; ni < 4; ++ni) {
          int col = wn - 128 + ni * 16 + l15;
          half4_t h;
          h[0] = (half_t)acc[mi][ni][0]; h[1] = (half_t)acc[mi][ni][1];
          h[2] = (half_t)acc[mi][ni][2]; h[3] = (half_t)acc[mi][ni][3];
          *(half4_t*)(kvT + col * KVPAD + row0) = h;
        }
      }
    }
  }
  asm volatile("s_waitcnt lgkmcnt(0)" ::: "memory");
  __builtin_amdgcn_s_barrier(); FENCE;   // E3: attn + vv visible

  // ---- attnOut -> aO16 (vectorized: half4 v, float4 attn broadcasts) ----
  if (tid < 384) {
    int g = tid >> 7, dcol = tid & 127, hh = dcol >> 6;
    const float4* at4 = (const float4*)(scs + (g * 2 + hh) * 40);
    const half_t* vcol = kvT + dcol * KVPAD + g * 40;
    float s = 0.f;
    #pragma unroll
    for (int n4 = 0; n4 < 10; ++n4) {
      float4 a4 = at4[n4];
      half4_t v = *(const half4_t*)(vcol + n4 * 4);
      s += a4.x * (float)v[0] + a4.y * (float)v[1]
         + a4.z * (float)v[2] + a4.w * (float)v[3];
    }
    aO16[g * 128 + dcol] = (half_t)s;
  }
  asm volatile("s_waitcnt lgkmcnt(0)" ::: "memory");
  __builtin_amdgcn_s_barrier(); FENCE;   // E4: aO16 visible; kvT dead

  // ---- FFN via MFMA on waves 0-3: h1 = relu(aO*W1a + src*W1b) ----
  // A-frag: lane(l15,q4) = A[row=l15][k=q4*8+e]; rows 3..15 clamped to row 0
  // (their acc rows are never read). B-frags from global 8-pack (L2-hot).
  {
    const int ar = (l15 < 3) ? l15 : 0;
    if (wv < 4) {
      const int ni0 = wv * 2;
      floatx4 facc0 = (floatx4){0.f, 0.f, 0.f, 0.f};
      floatx4 facc1 = (floatx4){0.f, 0.f, 0.f, 0.f};
      #pragma unroll
      for (int kc = 0; kc < 4; ++kc) {
        half8 a1 = *(const half8*)(aO16 + ar * 128 + kc * 32 + q4 * 8);
        half8 a2 = *(const half8*)(s16  + ar * 128 + kc * 32 + q4 * 8);
        int kb = (kc * 4 + q4) * 128;
        half8 b1a = *(const half8*)(W1a4_l + (size_t)(kb + ni0 * 16 + l15) * 8);
        half8 b1b = *(const half8*)(W1a4_l + (size_t)(kb + ni0 * 16 + 16 + l15) * 8);
        half8 b2a = *(const half8*)(W1b4_l + (size_t)(kb + ni0 * 16 + l15) * 8);
        half8 b2b = *(const half8*)(W1b4_l + (size_t)(kb + ni0 * 16 + 16 + l15) * 8);
        facc0 = __builtin_amdgcn_mfma_f32_16x16x32_f16(a1, b1a, facc0, 0, 0, 0);
        facc1 = __builtin_amdgcn_mfma_f32_16x16x32_f16(a1, b1b, facc1, 0, 0, 0);
        facc0 = __builtin_amdgcn_mfma_f32_16x16x32_f16(a2, b2a, facc0, 0, 0, 0);
        facc1 = __builtin_amdgcn_mfma_f32_16x16x32_f16(a2, b2b, facc1, 0, 0, 0);
      }
      // C layout: row = q4*4 + e, col = l15 -> rows 0..2 live in q4==0 lanes
      if (q4 == 0) {
        #pragma unroll
        for (int e = 0; e < 3; ++e) {
          h116[e * 128 + ni0 * 16 + l15]       = (half_t)fmaxf(facc0[e], 0.f);
          h116[e * 128 + (ni0 + 1) * 16 + l15] = (half_t)fmaxf(facc1[e], 0.f);
        }
      }
    }
  }
  asm volatile("s_waitcnt lgkmcnt(0)" ::: "memory");
  __builtin_amdgcn_s_barrier(); FENCE;   // E5: h116 visible

  // ---- fc2 via MFMA on waves 0-3; write out directly ----
  {
    const int ar = (l15 < 3) ? l15 : 0;
    if (wv < 4) {
      const int ni0 = wv * 2;
      floatx4 facc0 = (floatx4){0.f, 0.f, 0.f, 0.f};
      floatx4 facc1 = (floatx4){0.f, 0.f, 0.f, 0.f};
      #pragma unroll
      for (int kc = 0; kc < 4; ++kc) {
        half8 a = *(const half8*)(h116 + ar * 128 + kc * 32 + q4 * 8);
        int kb = (kc * 4 + q4) * 128;
        half8 ba = *(const half8*)(W24_l + (size_t)(kb + ni0 * 16 + l15) * 8);
        half8 bb = *(const half8*)(W24_l + (size_t)(kb + ni0 * 16 + 16 + l15) * 8);
        facc0 = __builtin_amdgcn_mfma_f32_16x16x32_f16(a, ba, facc0, 0, 0, 0);
        facc1 = __builtin_amdgcn_mfma_f32_16x16x32_f16(a, bb, facc1, 0, 0, 0);
      }
      if (q4 == 0) {
        #pragma unroll
        for (int e = 0; e < 3; ++e) {
          if (L1DIR) {
            out32[(size_t)(bbase + e) * 128 + ni0 * 16 + l15]       = facc0[e];
            out32[(size_t)(bbase + e) * 128 + (ni0 + 1) * 16 + l15] = facc1[e];
          } else {
            out16[(size_t)(bbase + e) * 128 + ni0 * 16 + l15]       = (half_t)facc0[e];
            out16[(size_t)(bbase + e) * 128 + (ni0 + 1) * 16 + l15] = (half_t)facc1[e];
          }
        }
      }
    }
  }
#undef AB
#undef BB
#undef FENCE
}

// ---------------------------------------------------------------------------
extern "C" void kernel_launch(void* const* d_in, const int* in_sizes, int n_in,
                              void* d_out, int out_size, void* d_ws, size_t ws_size,
                              hipStream_t stream) {
  const float* nf      = (const float*)d_in[0];
  const float* ef      = (const float*)d_in[1];
  const float* tw      = (const float*)d_in[2];
  const float* tb      = (const float*)d_in[3];
  const float* Wq      = (const float*)d_in[4];
  const float* Wk      = (const float*)d_in[5];
  const float* Wv      = (const float*)d_in[6];
  const float* Wo      = (const float*)d_in[7];
  const float* fc1     = (const float*)d_in[8];
  const float* fc2     = (const float*)d_in[9];
  const int*   srcn    = (const int*)d_in[10];
  const float* ts      = (const float*)d_in[11];
  const int*   neigh2  = (const int*)d_in[12];
  const int*   eidx2   = (const int*)d_in[13];
  const float* etimes2 = (const float*)d_in[14];
  const int*   neigh1  = (const int*)d_in[15];
  const int*   eidx1   = (const int*)d_in[16];
  const float* etimes1 = (const float*)d_in[17];

  char* ws = (char*)d_ws;
  half_t* nf16   = (half_t*)(ws + WS_NF16);
  half_t* emb116 = (half_t*)(ws + WS_EMB16);
  half_t* WkvT16 = (half_t*)(ws + WS_WKVT);
  half_t* Wq4    = (half_t*)(ws + WS_WQ4);
  half_t* W1a4   = (half_t*)(ws + WS_W1A4);
  half_t* W1b4   = (half_t*)(ws + WS_W1B4);
  half_t* W24    = (half_t*)(ws + WS_W24);
  float*  qbias  = (float*)(ws + WS_QBIAS);
  float*  woftmp = (float*)(ws + WS_WOFTMP);
  half_t* zrow   = (half_t*)(ws + WS_ZERO);
  half_t* ef16   = (half_t*)(ws + WS_EF16);

  bool full = (ws_size >= WS_TOTAL_FULL);

  cvt_kernel<<<dim3(2048), dim3(256), 0, stream>>>(nf, nf16, 1600000);
  if (full)
    cvt_kernel<<<dim3(4096), dim3(256), 0, stream>>>(ef, ef16, 8000000);
  precompute_w<<<dim3(1281), dim3(256), 0, stream>>>(
      Wq, Wk, Wv, Wo, fc1, fc2, tb, WkvT16, qbias, woftmp, Wq4, W1b4, W24, zrow);
  precompute_w2<<<dim3(128), dim3(256), 0, stream>>>(woftmp, W1a4);

  if (full) {
    hop_kernel<true, false><<<dim3(4000), dim3(512), 0, stream>>>(
        nf, nf16, ef16, ef, neigh2, ts, neigh1, eidx1, etimes1, tw, tb,
        Wq4, qbias, WkvT16, W1a4, W1b4, W24, zrow, emb116, nullptr);
    hop_kernel<true, true><<<dim3(100), dim3(512), 0, stream>>>(
        nf, emb116, ef16, ef, srcn, ts, neigh2, eidx2, etimes2, tw, tb,
        Wq4 + 16384, qbias + 128, WkvT16 + 98304, W1a4 + 16384, W1b4 + 16384,
        W24 + 16384, zrow, emb116, (float*)d_out);
  } else {
    hop_kernel<false, false><<<dim3(4000), dim3(512), 0, stream>>>(
        nf, nf16, ef16, ef, neigh2, ts, neigh1, eidx1, etimes1, tw, tb,
        Wq4, qbias, WkvT16, W1a4, W1b4, W24, zrow, emb116, nullptr);
    hop_kernel<false, true><<<dim3(100), dim3(512), 0, stream>>>(
        nf, emb116, ef16, ef, srcn, ts, neigh2, eidx2, etimes2, tw, tb,
        Wq4 + 16384, qbias + 128, WkvT16 + 98304, W1a4 + 16384, W1b4 + 16384,
        W24 + 16384, zrow, emb116, (float*)d_out);
  }
}